// Round 6
// baseline (97.057 us; speedup 1.0000x reference)
//
#include <hip/hip_runtime.h>
#include <stdint.h>

// ---- problem constants ----
#define NPARTS 16
#define NK1    257            // rows per part (hash values 0..256)
#define ROWS   4112           // 257*16 distinct embedding rows
#define MPAD   4224           // 66*64, padded GEMM M
#define VAE    768
#define ODIM   1024
#define BROWS  65536          // 4096*16 output rows

typedef __attribute__((ext_vector_type(4))) float f32x4;
typedef __attribute__((ext_vector_type(8))) short s16x8;

static __device__ __forceinline__ unsigned short f2bf(float f) {
  union { float f; unsigned u; } v; v.f = f;
  unsigned x = v.u;
  unsigned r = x + 0x7FFFu + ((x >> 16) & 1u);   // RNE
  return (unsigned short)(r >> 16);
}

static __device__ __forceinline__ void gload_lds16(const void* g, void* l) {
  __builtin_amdgcn_global_load_lds(
      (const __attribute__((address_space(1))) unsigned int*)g,
      (__attribute__((address_space(3))) unsigned int*)l, 16, 0, 0);
}

// ---------------- prep: transpose-cast W1 only (emb cast fused into GEMM1) ----
// 768 blocks: 24 k-tiles x 32 n-tiles of 32x32
__global__ __launch_bounds__(256) void prep_kernel(
    const float* __restrict__ W1, unsigned short* __restrict__ w1t) {
  __shared__ unsigned short tile[32][33];
  const int tid = threadIdx.x;
  const int tb  = blockIdx.x;
  const int nkt = VAE / 32;
  const int tk = (tb % nkt) * 32;
  const int tn = (tb / nkt) * 32;
  const int r  = tid >> 3;                 // k-local
  const int c4 = (tid & 7) * 4;            // n-local
  const float4 v = *(const float4*)(W1 + (size_t)(tk + r) * ODIM + tn + c4);
  tile[r][c4 + 0] = f2bf(v.x);
  tile[r][c4 + 1] = f2bf(v.y);
  tile[r][c4 + 2] = f2bf(v.z);
  tile[r][c4 + 3] = f2bf(v.w);
  __syncthreads();
  ushort4 o;
  o.x = tile[c4 + 0][r];
  o.y = tile[c4 + 1][r];
  o.z = tile[c4 + 2][r];
  o.w = tile[c4 + 3][r];
  *(ushort4*)(w1t + (size_t)(tn + r) * VAE + tk + c4) = o;
}

// ---------------- GEMM1: H = relu(emb_f32 * w1t^T + b1) -> bf16 ----------------
// R3-proven core: 64x128 tile, BK=64, 2-buffer 48KB (3 blocks/CU), XOR-swizzled
// LDS [rule #21]. A (emb) is fp32 in global: reg-staged (load->cvt->ds_write),
// fusing the bf16 cast. B (w1t) stays global_load_lds with pre-swizzled source.
// z==1 blocks transpose-cast W2 -> w2dst (overlapped with GEMM compute).
__global__ __launch_bounds__(256) void gemm1_kernel(
    const float* __restrict__ emb, const unsigned short* __restrict__ BT,
    const float* __restrict__ bias, unsigned short* __restrict__ outB,
    const float* __restrict__ W2src, unsigned short* __restrict__ w2dst) {
  __shared__ __align__(16) unsigned short smem[2 * 12288];   // 48 KB
  const int tid = threadIdx.x;

  if (blockIdx.z == 1) {
    if (blockIdx.y >= 32) return;
    unsigned short (*ttile)[132] = (unsigned short (*)[132])smem;
    const int tk = blockIdx.y * 32, tn = blockIdx.x * 128;
#pragma unroll
    for (int q = 0; q < 4; ++q) {
      const int row = (tid >> 5) + q * 8, c4 = (tid & 31) * 4;
      const float4 v = *(const float4*)(W2src + (size_t)(tk + row) * ODIM + tn + c4);
      ttile[row][c4 + 0] = f2bf(v.x); ttile[row][c4 + 1] = f2bf(v.y);
      ttile[row][c4 + 2] = f2bf(v.z); ttile[row][c4 + 3] = f2bf(v.w);
    }
    __syncthreads();
#pragma unroll
    for (int q = 0; q < 4; ++q) {
      const int n = (tid >> 3) + q * 32, k4 = (tid & 7) * 4;
      ushort4 o;
      o.x = ttile[k4 + 0][n]; o.y = ttile[k4 + 1][n];
      o.z = ttile[k4 + 2][n]; o.w = ttile[k4 + 3][n];
      *(ushort4*)(w2dst + (size_t)(tn + n) * ODIM + tk + k4) = o;
    }
    return;
  }

  const int lane = tid & 63;
  const int wave = tid >> 6;
  const int wc   = wave * 32;
  const int brow = blockIdx.y * 64;
  const int bcol = blockIdx.x * 128;
  const int la   = lane & 15;
  const int hi   = lane >> 4;

  f32x4 acc[4][2];
#pragma unroll
  for (int m = 0; m < 4; ++m)
#pragma unroll
    for (int n = 0; n < 2; ++n)
#pragma unroll
      for (int r = 0; r < 4; ++r) acc[m][n][r] = 0.f;

  // B staging (gload_lds, pre-swizzled source)
  const int srow = tid >> 3;                       // 0..31
  const int skb  = (tid & 7) ^ (srow & 7);         // swizzled k-block
  const unsigned short* gB = BT + (size_t)(bcol + srow) * VAE + skb * 8;
  // A staging (reg): thread t covers row=t>>2, k-span [(t&3)*16, +16)
  const int arow = tid >> 2;
  const int ak   = (tid & 3) * 16;
  const int kb0  = ((tid & 3) * 2) ^ (arow & 7);   // swizzled kb of first 8
  const int kb1  = ((tid & 3) * 2 + 1) ^ (arow & 7);
  const bool aok = (brow + arow) < ROWS;
  const float* gA = emb + (size_t)(brow + arow) * VAE + ak;

  auto stage = [&](int b, int kt) {
    unsigned short* lb_ = smem + b * 12288 + 4096 + tid * 8;
    gload_lds16(gB + kt, lb_);
    gload_lds16(gB + kt + 32 * VAE, lb_ + 2048);
    gload_lds16(gB + kt + 64 * VAE, lb_ + 4096);
    gload_lds16(gB + kt + 96 * VAE, lb_ + 6144);
    float4 f0, f1, f2, f3;
    if (aok) {
      f0 = *(const float4*)(gA + kt);
      f1 = *(const float4*)(gA + kt + 4);
      f2 = *(const float4*)(gA + kt + 8);
      f3 = *(const float4*)(gA + kt + 12);
    } else {
      f0 = f1 = f2 = f3 = float4{0.f, 0.f, 0.f, 0.f};
    }
    s16x8 p0, p1;
    p0[0] = f2bf(f0.x); p0[1] = f2bf(f0.y); p0[2] = f2bf(f0.z); p0[3] = f2bf(f0.w);
    p0[4] = f2bf(f1.x); p0[5] = f2bf(f1.y); p0[6] = f2bf(f1.z); p0[7] = f2bf(f1.w);
    p1[0] = f2bf(f2.x); p1[1] = f2bf(f2.y); p1[2] = f2bf(f2.z); p1[3] = f2bf(f2.w);
    p1[4] = f2bf(f3.x); p1[5] = f2bf(f3.y); p1[6] = f2bf(f3.z); p1[7] = f2bf(f3.w);
    unsigned short* la_ = smem + b * 12288 + arow * 64;
    *(s16x8*)(la_ + kb0 * 8) = p0;
    *(s16x8*)(la_ + kb1 * 8) = p1;
  };

  stage(0, 0);
  __syncthreads();

  const int NT = VAE / 64;   // 12
  for (int t = 0; t < NT; ++t) {
    const int cur = t & 1;
    if (t + 1 < NT) stage(cur ^ 1, (t + 1) * 64);   // prefetch overlaps compute

    const unsigned short* As = smem + cur * 12288;
    const unsigned short* Bs = As + 4096;
    s16x8 af[4][2], bf[2][2];
#pragma unroll
    for (int m = 0; m < 4; ++m)
#pragma unroll
      for (int ks = 0; ks < 2; ++ks)
        af[m][ks] = *(const s16x8*)(As + (m * 16 + la) * 64 +
                                    (((ks * 4 + hi) ^ (la & 7)) * 8));
#pragma unroll
    for (int n = 0; n < 2; ++n)
#pragma unroll
      for (int ks = 0; ks < 2; ++ks)
        bf[n][ks] = *(const s16x8*)(Bs + (wc + n * 16 + la) * 64 +
                                    (((ks * 4 + hi) ^ (la & 7)) * 8));
#pragma unroll
    for (int m = 0; m < 4; ++m)
#pragma unroll
      for (int n = 0; n < 2; ++n)
#pragma unroll
        for (int ks = 0; ks < 2; ++ks)
          acc[m][n] = __builtin_amdgcn_mfma_f32_16x16x32_bf16(af[m][ks], bf[n][ks],
                                                              acc[m][n], 0, 0, 0);
    __syncthreads();   // drains vmcnt+lgkmcnt; protects both buffers
  }

  // epilogue: C/D layout col=lane&15, row=(lane>>4)*4+reg  [m89-verified]
#pragma unroll
  for (int m = 0; m < 4; ++m) {
    const int row0 = brow + m * 16 + hi * 4;
#pragma unroll
    for (int n = 0; n < 2; ++n) {
      const int col = bcol + wc + n * 16 + la;
      const float bv = bias[col];
#pragma unroll
      for (int r = 0; r < 4; ++r) {
        float v = acc[m][n][r] + bv;
        v = v > 0.f ? v : 0.f;
        outB[(size_t)(row0 + r) * ODIM + col] = f2bf(v);
      }
    }
  }
}

// ---------------- GEMM2: T = H * w2t^T + b2 + pe[row/257]  (R3 core, unchanged) ----
__global__ __launch_bounds__(256) void gemm2_kernel(
    const unsigned short* __restrict__ A, const unsigned short* __restrict__ BT,
    const float* __restrict__ bias, const float* __restrict__ pe,
    float* __restrict__ outF) {
  __shared__ __align__(16) unsigned short smem[2 * 12288];   // 48 KB
  const int tid  = threadIdx.x;
  const int lane = tid & 63;
  const int wave = tid >> 6;
  const int wc   = wave * 32;
  const int brow = blockIdx.y * 64;
  const int bcol = blockIdx.x * 128;
  const int la   = lane & 15;
  const int hi   = lane >> 4;
  const int K    = ODIM;

  f32x4 acc[4][2];
#pragma unroll
  for (int m = 0; m < 4; ++m)
#pragma unroll
    for (int n = 0; n < 2; ++n)
#pragma unroll
      for (int r = 0; r < 4; ++r) acc[m][n][r] = 0.f;

  const int srow = tid >> 3;
  const int skb  = (tid & 7) ^ (srow & 7);
  const unsigned short* gA = A + (size_t)(brow + srow) * K + skb * 8;
  const unsigned short* gB = BT + (size_t)(bcol + srow) * K + skb * 8;

#define STAGE(b, kt)                                              \
  {                                                               \
    unsigned short* la_ = smem + (b) * 12288 + tid * 8;           \
    unsigned short* lb_ = la_ + 4096;                             \
    gload_lds16(gA + (kt), la_);                                  \
    gload_lds16(gA + (kt) + 32 * K, la_ + 2048);                  \
    gload_lds16(gB + (kt), lb_);                                  \
    gload_lds16(gB + (kt) + 32 * K, lb_ + 2048);                  \
    gload_lds16(gB + (kt) + 64 * K, lb_ + 4096);                  \
    gload_lds16(gB + (kt) + 96 * K, lb_ + 6144);                  \
  }

  STAGE(0, 0);
  __syncthreads();

  const int NT = K / 64;   // 16
  for (int t = 0; t < NT; ++t) {
    const int cur = t & 1;
    if (t + 1 < NT) STAGE(cur ^ 1, (t + 1) * 64);

    const unsigned short* As = smem + cur * 12288;
    const unsigned short* Bs = As + 4096;
    s16x8 af[4][2], bf[2][2];
#pragma unroll
    for (int m = 0; m < 4; ++m)
#pragma unroll
      for (int ks = 0; ks < 2; ++ks)
        af[m][ks] = *(const s16x8*)(As + (m * 16 + la) * 64 +
                                    (((ks * 4 + hi) ^ (la & 7)) * 8));
#pragma unroll
    for (int n = 0; n < 2; ++n)
#pragma unroll
      for (int ks = 0; ks < 2; ++ks)
        bf[n][ks] = *(const s16x8*)(Bs + (wc + n * 16 + la) * 64 +
                                    (((ks * 4 + hi) ^ (la & 7)) * 8));
#pragma unroll
    for (int m = 0; m < 4; ++m)
#pragma unroll
      for (int n = 0; n < 2; ++n)
#pragma unroll
        for (int ks = 0; ks < 2; ++ks)
          acc[m][n] = __builtin_amdgcn_mfma_f32_16x16x32_bf16(af[m][ks], bf[n][ks],
                                                              acc[m][n], 0, 0, 0);
    __syncthreads();
  }
#undef STAGE

#pragma unroll
  for (int m = 0; m < 4; ++m) {
    const int row0 = brow + m * 16 + hi * 4;
#pragma unroll
    for (int n = 0; n < 2; ++n) {
      const int col = bcol + wc + n * 16 + la;
      const float bv = bias[col];
#pragma unroll
      for (int r = 0; r < 4; ++r) {
        const int row = row0 + r;
        int p = row / NK1;
        if (p > NPARTS - 1) p = NPARTS - 1;   // padded rows: never gathered
        outF[(size_t)row * ODIM + col] = acc[m][n][r] + bv + pe[(size_t)p * ODIM + col];
      }
    }
  }
}

// ---------------- gather: out[row] = T[hash + (row&15)*257] ----------------
// XCD-affinity: blockIdx%8 (round-robin -> XCD) handles parts {2x,2x+1}, so each
// XCD's T read set is 2.06 MB < 4 MB L2 -> reads L2-hit under the HBM write stream.
__global__ __launch_bounds__(256) void gather_kernel(const int* __restrict__ hashes,
                                                     const float* __restrict__ T,
                                                     float* __restrict__ out) {
  const int xcd  = blockIdx.x & 7;
  const int bi   = blockIdx.x >> 3;            // 0..255
  const int wave = threadIdx.x >> 6;
  const int lane = threadIdx.x & 63;
  const int wl   = bi * 4 + wave;              // 0..1023
  const int p0   = xcd * 2;
#pragma unroll
  for (int i = 0; i < 8; ++i) {
    const int r     = wl + i * 1024;           // 0..8191
    const int batch = r >> 1;
    const int p     = p0 + (r & 1);
    const int orow  = batch * NPARTS + p;
    const int h = __builtin_amdgcn_readfirstlane(hashes[orow]);
    const f32x4* __restrict__ src = (const f32x4*)(T + (size_t)(h + p * NK1) * ODIM);
    f32x4* __restrict__ dst = (f32x4*)(out + (size_t)orow * ODIM);
#pragma unroll
    for (int j = 0; j < 4; ++j) {
      f32x4 v = src[lane + j * 64];
      __builtin_nontemporal_store(v, dst + lane + j * 64);
    }
  }
}

// ---------------- launch ----------------
extern "C" void kernel_launch(void* const* d_in, const int* in_sizes, int n_in,
                              void* d_out, int out_size, void* d_ws, size_t ws_size,
                              hipStream_t stream) {
  const int*   hashes = (const int*)d_in[0];
  const float* emb    = (const float*)d_in[1];
  const float* W1     = (const float*)d_in[2];
  const float* b1     = (const float*)d_in[3];
  const float* W2     = (const float*)d_in[4];
  const float* b2     = (const float*)d_in[5];
  const float* pe     = (const float*)d_in[6];
  float* out = (float*)d_out;

  char* ws = (char*)d_ws;
  unsigned short* w1t = (unsigned short*)(ws);                 // 1024*768*2  = 1,572,864
  unsigned short* w2t = (unsigned short*)(ws + 1572864);       // 1024*1024*2 = 2,097,152
  unsigned short* H   = (unsigned short*)(ws + 3670016);       // 4224*1024*2 = 8,650,752
  float*          T   = (float*)(ws + 12320768);               // 4224*1024*4 = 17,301,504

  prep_kernel<<<768, 256, 0, stream>>>(W1, w1t);

  // GEMM1 (z=0: 528 gemm blocks, emb cast fused) + W2 transpose (z=1: 256 blocks)
  gemm1_kernel<<<dim3(8, 66, 2), 256, 0, stream>>>(emb, w1t, b1, H, W2, w2t);

  gemm2_kernel<<<dim3(8, 66, 1), 256, 0, stream>>>(H, w2t, b2, pe, T);

  gather_kernel<<<2048, 256, 0, stream>>>(hashes, T, out);
}